// Round 3
// baseline (884.046 us; speedup 1.0000x reference)
//
#include <hip/hip_runtime.h>
#include <math.h>

#define NUM_STEPS 50

// Pin a wave-uniform float into an SGPR (VOP3 fma reads it as the single
// allowed scalar operand -> no VGPR cost, no v_mov per use).
__device__ __forceinline__ float sbc(float x) {
    return __int_as_float(__builtin_amdgcn_readfirstlane(__float_as_int(x)));
}

// f(z) = (a - b*|z|^2) * z  (complex); |z|^2 exactly real as in the reference.
// 8 VALU ops: 2 (|z|^2) + 2 (c = a - b*m) + 4 (c*z), negations free via VOP3 mods.
#define FEVAL(ZR, ZI, KR, KI, AR, AI, BR, BI)            \
    {                                                    \
        float m_  = fmaf((ZI), (ZI), (ZR) * (ZR));       \
        float cr_ = fmaf(-(BR), m_, (AR));               \
        float ci_ = fmaf(-(BI), m_, (AI));               \
        (KR) = fmaf(cr_, (ZR), -(ci_ * (ZI)));           \
        (KI) = fmaf(cr_, (ZI),  (ci_ * (ZR)));           \
    }

// One full DOPRI5 step for one element (40 fma of stage combos + 6 FEVAL = 88 ops)
#define STEP(ZR, ZI, AR, AI, BR, BI)                                            \
    {                                                                           \
        float k1r,k1i,k2r,k2i,k3r,k3i,k4r,k4i,k5r,k5i,k6r,k6i,tr,ti;            \
        FEVAL(ZR, ZI, k1r, k1i, AR, AI, BR, BI)                                 \
        tr = fmaf(hA21,k1r, ZR);                                                \
        ti = fmaf(hA21,k1i, ZI);                                                \
        FEVAL(tr, ti, k2r, k2i, AR, AI, BR, BI)                                 \
        tr = fmaf(hA31,k1r, fmaf(hA32,k2r, ZR));                                \
        ti = fmaf(hA31,k1i, fmaf(hA32,k2i, ZI));                                \
        FEVAL(tr, ti, k3r, k3i, AR, AI, BR, BI)                                 \
        tr = fmaf(hA41,k1r, fmaf(hA42,k2r, fmaf(hA43,k3r, ZR)));                \
        ti = fmaf(hA41,k1i, fmaf(hA42,k2i, fmaf(hA43,k3i, ZI)));                \
        FEVAL(tr, ti, k4r, k4i, AR, AI, BR, BI)                                 \
        tr = fmaf(hA51,k1r, fmaf(hA52,k2r, fmaf(hA53,k3r, fmaf(hA54,k4r, ZR)))); \
        ti = fmaf(hA51,k1i, fmaf(hA52,k2i, fmaf(hA53,k3i, fmaf(hA54,k4i, ZI)))); \
        FEVAL(tr, ti, k5r, k5i, AR, AI, BR, BI)                                 \
        tr = fmaf(hA61,k1r, fmaf(hA62,k2r, fmaf(hA63,k3r, fmaf(hA64,k4r, fmaf(hA65,k5r, ZR))))); \
        ti = fmaf(hA61,k1i, fmaf(hA62,k2i, fmaf(hA63,k3i, fmaf(hA64,k4i, fmaf(hA65,k5i, ZI))))); \
        FEVAL(tr, ti, k6r, k6i, AR, AI, BR, BI)                                 \
        ZR = fmaf(hB1,k1r, fmaf(hB3,k3r, fmaf(hB4,k4r, fmaf(hB5,k5r, fmaf(hB6,k6r, ZR))))); \
        ZI = fmaf(hB1,k1i, fmaf(hB3,k3i, fmaf(hB4,k4i, fmaf(hB5,k5i, fmaf(hB6,k6i, ZI))))); \
    }

// block=128 (2 waves): finest scheduling granularity that keeps full
// occupancy (16 blocks/CU x 2 waves = 32 waves/CU) -> fewer issue bubbles
// at block retirement boundaries than 256-thread blocks.
__global__ __launch_bounds__(128, 8) void hopf_dopri5_kernel(
    const float* __restrict__ re_z, const float* __restrict__ im_z,
    const float* __restrict__ re_a, const float* __restrict__ im_a,
    const float* __restrict__ re_b, const float* __restrict__ im_b,
    const int*  __restrict__ unts_p,
    float* __restrict__ out, int n)
{
    const int t = blockIdx.x * blockDim.x + threadIdx.x;
    const int i = t * 2;                 // 2 elements per thread (ILP=2: round-1 sweet spot)
    if (i >= n) return;

    // h = float32( (2*pi - 2*pi/unts) / 50 ) -- double, matching the reference
    const int unts = unts_p[0];
    const double t1 = 2.0 * M_PI - 2.0 * M_PI / (double)unts;
    const float h = sbc((float)(t1 / (double)NUM_STEPS));

    // Pre-scaled Dormand-Prince tableau, pinned to SGPRs
    const float hA21 = sbc(h * (float)(1.0/5.0));
    const float hA31 = sbc(h * (float)(3.0/40.0));
    const float hA32 = sbc(h * (float)(9.0/40.0));
    const float hA41 = sbc(h * (float)(44.0/45.0));
    const float hA42 = sbc(h * (float)(-56.0/15.0));
    const float hA43 = sbc(h * (float)(32.0/9.0));
    const float hA51 = sbc(h * (float)(19372.0/6561.0));
    const float hA52 = sbc(h * (float)(-25360.0/2187.0));
    const float hA53 = sbc(h * (float)(64448.0/6561.0));
    const float hA54 = sbc(h * (float)(-212.0/729.0));
    const float hA61 = sbc(h * (float)(9017.0/3168.0));
    const float hA62 = sbc(h * (float)(-355.0/33.0));
    const float hA63 = sbc(h * (float)(46732.0/5247.0));
    const float hA64 = sbc(h * (float)(49.0/176.0));
    const float hA65 = sbc(h * (float)(-5103.0/18656.0));
    const float hB1  = sbc(h * (float)(35.0/384.0));
    const float hB3  = sbc(h * (float)(500.0/1113.0));
    const float hB4  = sbc(h * (float)(125.0/192.0));
    const float hB5  = sbc(h * (float)(-2187.0/6784.0));
    const float hB6  = sbc(h * (float)(11.0/84.0));

    // 8 B/lane coalesced vector loads
    const float2 zr2 = *(const float2*)(re_z + i);
    const float2 zi2 = *(const float2*)(im_z + i);
    const float2 ar2 = *(const float2*)(re_a + i);
    const float2 ai2 = *(const float2*)(im_a + i);
    const float2 br2 = *(const float2*)(re_b + i);
    const float2 bi2 = *(const float2*)(im_b + i);

    float z0r = zr2.x, z1r = zr2.y;
    float z0i = zi2.x, z1i = zi2.y;

    #pragma unroll 1
    for (int s = 0; s < NUM_STEPS; ++s) {
        STEP(z0r, z0i, ar2.x, ai2.x, br2.x, bi2.x)
        STEP(z1r, z1i, ar2.y, ai2.y, br2.y, bi2.y)
    }

    // Output: stack([re, im]) -> first n reals, then n imags
    *(float2*)(out + i)     = make_float2(z0r, z1r);
    *(float2*)(out + n + i) = make_float2(z0i, z1i);
}

extern "C" void kernel_launch(void* const* d_in, const int* in_sizes, int n_in,
                              void* d_out, int out_size, void* d_ws, size_t ws_size,
                              hipStream_t stream) {
    const float* re_z = (const float*)d_in[0];
    const float* im_z = (const float*)d_in[1];
    const float* re_a = (const float*)d_in[2];
    const float* im_a = (const float*)d_in[3];
    const float* re_b = (const float*)d_in[4];
    const float* im_b = (const float*)d_in[5];
    // d_in[6] = stp (unused by the reference)
    const int*   unts = (const int*)d_in[7];
    float* out = (float*)d_out;

    const int n = in_sizes[0];                 // 2048*2048
    const int threads = (n + 1) / 2;           // 2 elements per thread
    const int block = 128;
    const int grid = (threads + block - 1) / block;

    hopf_dopri5_kernel<<<grid, block, 0, stream>>>(re_z, im_z, re_a, im_a,
                                                   re_b, im_b, unts, out, n);
}

// Round 4
// 453.589 us; speedup vs baseline: 1.9490x; 1.9490x over previous
//
#include <hip/hip_runtime.h>
#include <math.h>

#define NUM_STEPS 50

// Pin a wave-uniform float into an SGPR (VOP3 fma reads it as the single
// allowed scalar operand -> no VGPR cost, no v_mov per use).
__device__ __forceinline__ float sbc(float x) {
    return __int_as_float(__builtin_amdgcn_readfirstlane(__float_as_int(x)));
}

// f(z) = (a - b*|z|^2) * z  (complex); |z|^2 exactly real as in the reference.
// 8 VALU ops: 2 (|z|^2) + 2 (c = a - b*m) + 4 (c*z), negations free via VOP3 mods.
#define FEVAL(ZR, ZI, KR, KI, AR, AI, BR, BI)            \
    {                                                    \
        float m_  = fmaf((ZI), (ZI), (ZR) * (ZR));       \
        float cr_ = fmaf(-(BR), m_, (AR));               \
        float ci_ = fmaf(-(BI), m_, (AI));               \
        (KR) = fmaf(cr_, (ZR), -(ci_ * (ZI)));           \
        (KI) = fmaf(cr_, (ZI),  (ci_ * (ZR)));           \
    }

// One full DOPRI5 step for one element (40 fma stage combos + 6 FEVAL = 88 ops)
#define STEP(ZR, ZI, AR, AI, BR, BI)                                            \
    {                                                                           \
        float k1r,k1i,k2r,k2i,k3r,k3i,k4r,k4i,k5r,k5i,k6r,k6i,tr,ti;            \
        FEVAL(ZR, ZI, k1r, k1i, AR, AI, BR, BI)                                 \
        tr = fmaf(hA21,k1r, ZR);                                                \
        ti = fmaf(hA21,k1i, ZI);                                                \
        FEVAL(tr, ti, k2r, k2i, AR, AI, BR, BI)                                 \
        tr = fmaf(hA31,k1r, fmaf(hA32,k2r, ZR));                                \
        ti = fmaf(hA31,k1i, fmaf(hA32,k2i, ZI));                                \
        FEVAL(tr, ti, k3r, k3i, AR, AI, BR, BI)                                 \
        tr = fmaf(hA41,k1r, fmaf(hA42,k2r, fmaf(hA43,k3r, ZR)));                \
        ti = fmaf(hA41,k1i, fmaf(hA42,k2i, fmaf(hA43,k3i, ZI)));                \
        FEVAL(tr, ti, k4r, k4i, AR, AI, BR, BI)                                 \
        tr = fmaf(hA51,k1r, fmaf(hA52,k2r, fmaf(hA53,k3r, fmaf(hA54,k4r, ZR)))); \
        ti = fmaf(hA51,k1i, fmaf(hA52,k2i, fmaf(hA53,k3i, fmaf(hA54,k4i, ZI)))); \
        FEVAL(tr, ti, k5r, k5i, AR, AI, BR, BI)                                 \
        tr = fmaf(hA61,k1r, fmaf(hA62,k2r, fmaf(hA63,k3r, fmaf(hA64,k4r, fmaf(hA65,k5r, ZR))))); \
        ti = fmaf(hA61,k1i, fmaf(hA62,k2i, fmaf(hA63,k3i, fmaf(hA64,k4i, fmaf(hA65,k5i, ZI))))); \
        FEVAL(tr, ti, k6r, k6i, AR, AI, BR, BI)                                 \
        ZR = fmaf(hB1,k1r, fmaf(hB3,k3r, fmaf(hB4,k4r, fmaf(hB5,k5r, fmaf(hB6,k6r, ZR))))); \
        ZI = fmaf(hB1,k1i, fmaf(hB3,k3i, fmaf(hB4,k4i, fmaf(hB5,k5i, fmaf(hB6,k6i, ZI))))); \
    }

// block=256, NO min-waves bound: round-3 showed any register cap below ~40
// VGPR causes catastrophic scratch spills (WRITE_SIZE 32->180 MB, 2.6x dur).
// Round-1 config (VGPR=40, 8 waves/SIMD achievable) is the proven optimum.
__global__ __launch_bounds__(256) void hopf_dopri5_kernel(
    const float* __restrict__ re_z, const float* __restrict__ im_z,
    const float* __restrict__ re_a, const float* __restrict__ im_a,
    const float* __restrict__ re_b, const float* __restrict__ im_b,
    const int*  __restrict__ unts_p,
    float* __restrict__ out, int n)
{
    const int t = blockIdx.x * blockDim.x + threadIdx.x;
    const int i = t * 2;                 // 2 elements per thread (ILP=2: proven sweet spot)
    if (i >= n) return;

    // h = float32( (2*pi - 2*pi/unts) / 50 ) -- double, matching the reference
    const int unts = unts_p[0];
    const double t1 = 2.0 * M_PI - 2.0 * M_PI / (double)unts;
    const float h = sbc((float)(t1 / (double)NUM_STEPS));

    // Pre-scaled Dormand-Prince tableau, pinned to SGPRs
    const float hA21 = sbc(h * (float)(1.0/5.0));
    const float hA31 = sbc(h * (float)(3.0/40.0));
    const float hA32 = sbc(h * (float)(9.0/40.0));
    const float hA41 = sbc(h * (float)(44.0/45.0));
    const float hA42 = sbc(h * (float)(-56.0/15.0));
    const float hA43 = sbc(h * (float)(32.0/9.0));
    const float hA51 = sbc(h * (float)(19372.0/6561.0));
    const float hA52 = sbc(h * (float)(-25360.0/2187.0));
    const float hA53 = sbc(h * (float)(64448.0/6561.0));
    const float hA54 = sbc(h * (float)(-212.0/729.0));
    const float hA61 = sbc(h * (float)(9017.0/3168.0));
    const float hA62 = sbc(h * (float)(-355.0/33.0));
    const float hA63 = sbc(h * (float)(46732.0/5247.0));
    const float hA64 = sbc(h * (float)(49.0/176.0));
    const float hA65 = sbc(h * (float)(-5103.0/18656.0));
    const float hB1  = sbc(h * (float)(35.0/384.0));
    const float hB3  = sbc(h * (float)(500.0/1113.0));
    const float hB4  = sbc(h * (float)(125.0/192.0));
    const float hB5  = sbc(h * (float)(-2187.0/6784.0));
    const float hB6  = sbc(h * (float)(11.0/84.0));

    // 8 B/lane coalesced vector loads
    const float2 zr2 = *(const float2*)(re_z + i);
    const float2 zi2 = *(const float2*)(im_z + i);
    const float2 ar2 = *(const float2*)(re_a + i);
    const float2 ai2 = *(const float2*)(im_a + i);
    const float2 br2 = *(const float2*)(re_b + i);
    const float2 bi2 = *(const float2*)(im_b + i);

    float z0r = zr2.x, z1r = zr2.y;
    float z0i = zi2.x, z1i = zi2.y;

    #pragma unroll 1
    for (int s = 0; s < NUM_STEPS; ++s) {
        STEP(z0r, z0i, ar2.x, ai2.x, br2.x, bi2.x)
        STEP(z1r, z1i, ar2.y, ai2.y, br2.y, bi2.y)
    }

    // Output: stack([re, im]) -> first n reals, then n imags
    *(float2*)(out + i)     = make_float2(z0r, z1r);
    *(float2*)(out + n + i) = make_float2(z0i, z1i);
}

extern "C" void kernel_launch(void* const* d_in, const int* in_sizes, int n_in,
                              void* d_out, int out_size, void* d_ws, size_t ws_size,
                              hipStream_t stream) {
    const float* re_z = (const float*)d_in[0];
    const float* im_z = (const float*)d_in[1];
    const float* re_a = (const float*)d_in[2];
    const float* im_a = (const float*)d_in[3];
    const float* re_b = (const float*)d_in[4];
    const float* im_b = (const float*)d_in[5];
    // d_in[6] = stp (unused by the reference)
    const int*   unts = (const int*)d_in[7];
    float* out = (float*)d_out;

    const int n = in_sizes[0];                 // 2048*2048
    const int threads = (n + 1) / 2;           // 2 elements per thread
    const int block = 256;
    const int grid = (threads + block - 1) / block;

    hopf_dopri5_kernel<<<grid, block, 0, stream>>>(re_z, im_z, re_a, im_a,
                                                   re_b, im_b, unts, out, n);
}

// Round 5
// 419.231 us; speedup vs baseline: 2.1087x; 1.0820x over previous
//
#include <hip/hip_runtime.h>
#include <math.h>

#define NUM_STEPS 50

// ROOFLINE NOTES (rounds 1-4):
//  - compute-bound on fp32 VALU: 88 ops/elem/step x 50 steps x 4.19M elems;
//    342 us = 5.39e13 lane-ops/s ~ 105% of measured full-chip FMA rate (m07:
//    103 TF). Gap to 235 us spec floor = sustained-clock throttle, not slack.
//  - ILP=2 / block=256 / VGPR=40 is the measured optimum:
//      R2: ILP=4 (VGPR 60)            -> 357 us (neutral-regression)
//      R3: __launch_bounds__(256->128,8) -> VGPR 32, scratch spills, 884 us
//      R4: SGPR-pinned coefficients   -> 350 us (busy-cycles UP; compiler
//          already folds coeffs into VOP3 scalar slots unaided)
//  - HBM 3% of peak; no fp32 MFMA on CDNA4; packed fp32 = same VALU cycles;
//    bf16/analytic paths fail accuracy (1e4x per-step error amplification).

// f(z) = (a - b*|z|^2) * z   (complex), |z|^2 exactly real as in the reference
__device__ __forceinline__ void feval(float ar, float ai, float br, float bi,
                                      float zr, float zi,
                                      float& kr, float& ki)
{
    float m  = fmaf(zi, zi, zr * zr);   // |z|^2
    float cr = fmaf(-br, m, ar);        // a - b*m
    float ci = fmaf(-bi, m, ai);
    kr = fmaf(cr, zr, -(ci * zi));      // c * z
    ki = fmaf(cr, zi,  (ci * zr));
}

__global__ __launch_bounds__(256) void hopf_dopri5_kernel(
    const float* __restrict__ re_z, const float* __restrict__ im_z,
    const float* __restrict__ re_a, const float* __restrict__ im_a,
    const float* __restrict__ re_b, const float* __restrict__ im_b,
    const int*  __restrict__ unts_p,
    float* __restrict__ out, int n)
{
    const int t = blockIdx.x * blockDim.x + threadIdx.x;
    const int i = t * 2;                 // 2 elements per thread
    if (i >= n) return;

    // h = float32( (2*pi - 2*pi/unts) / 50 )  -- computed in double like the reference
    const int unts = unts_p[0];
    const double t1 = 2.0 * M_PI - 2.0 * M_PI / (double)unts;
    const float h = (float)(t1 / (double)NUM_STEPS);

    // Pre-scaled Dormand-Prince tableau (h * A_ij), uniform -> compiler handles
    const float hA21 = h * (float)(1.0/5.0);
    const float hA31 = h * (float)(3.0/40.0),      hA32 = h * (float)(9.0/40.0);
    const float hA41 = h * (float)(44.0/45.0),     hA42 = h * (float)(-56.0/15.0),
                hA43 = h * (float)(32.0/9.0);
    const float hA51 = h * (float)(19372.0/6561.0),  hA52 = h * (float)(-25360.0/2187.0),
                hA53 = h * (float)(64448.0/6561.0),  hA54 = h * (float)(-212.0/729.0);
    const float hA61 = h * (float)(9017.0/3168.0),   hA62 = h * (float)(-355.0/33.0),
                hA63 = h * (float)(46732.0/5247.0),  hA64 = h * (float)(49.0/176.0),
                hA65 = h * (float)(-5103.0/18656.0);
    const float hB1  = h * (float)(35.0/384.0),      hB3  = h * (float)(500.0/1113.0),
                hB4  = h * (float)(125.0/192.0),     hB5  = h * (float)(-2187.0/6784.0),
                hB6  = h * (float)(11.0/84.0);

    // Vector loads: 8 B/lane, coalesced
    const float2 zr2 = *(const float2*)(re_z + i);
    const float2 zi2 = *(const float2*)(im_z + i);
    const float2 ar2 = *(const float2*)(re_a + i);
    const float2 ai2 = *(const float2*)(im_a + i);
    const float2 br2 = *(const float2*)(re_b + i);
    const float2 bi2 = *(const float2*)(im_b + i);

    float zr[2] = {zr2.x, zr2.y};
    float zi[2] = {zi2.x, zi2.y};
    const float ar[2] = {ar2.x, ar2.y};
    const float ai[2] = {ai2.x, ai2.y};
    const float br[2] = {br2.x, br2.y};
    const float bi[2] = {bi2.x, bi2.y};

    for (int s = 0; s < NUM_STEPS; ++s) {
        #pragma unroll
        for (int u = 0; u < 2; ++u) {
            float k1r,k1i,k2r,k2i,k3r,k3i,k4r,k4i,k5r,k5i,k6r,k6i;
            float tr, ti;
            const float Ar = ar[u], Ai = ai[u], Br = br[u], Bi = bi[u];
            float Zr = zr[u], Zi = zi[u];

            feval(Ar,Ai,Br,Bi, Zr,Zi, k1r,k1i);

            tr = fmaf(hA21,k1r, Zr);
            ti = fmaf(hA21,k1i, Zi);
            feval(Ar,Ai,Br,Bi, tr,ti, k2r,k2i);

            tr = fmaf(hA31,k1r, fmaf(hA32,k2r, Zr));
            ti = fmaf(hA31,k1i, fmaf(hA32,k2i, Zi));
            feval(Ar,Ai,Br,Bi, tr,ti, k3r,k3i);

            tr = fmaf(hA41,k1r, fmaf(hA42,k2r, fmaf(hA43,k3r, Zr)));
            ti = fmaf(hA41,k1i, fmaf(hA42,k2i, fmaf(hA43,k3i, Zi)));
            feval(Ar,Ai,Br,Bi, tr,ti, k4r,k4i);

            tr = fmaf(hA51,k1r, fmaf(hA52,k2r, fmaf(hA53,k3r, fmaf(hA54,k4r, Zr))));
            ti = fmaf(hA51,k1i, fmaf(hA52,k2i, fmaf(hA53,k3i, fmaf(hA54,k4i, Zi))));
            feval(Ar,Ai,Br,Bi, tr,ti, k5r,k5i);

            tr = fmaf(hA61,k1r, fmaf(hA62,k2r, fmaf(hA63,k3r, fmaf(hA64,k4r, fmaf(hA65,k5r, Zr)))));
            ti = fmaf(hA61,k1i, fmaf(hA62,k2i, fmaf(hA63,k3i, fmaf(hA64,k4i, fmaf(hA65,k5i, Zi)))));
            feval(Ar,Ai,Br,Bi, tr,ti, k6r,k6i);

            zr[u] = fmaf(hB1,k1r, fmaf(hB3,k3r, fmaf(hB4,k4r, fmaf(hB5,k5r, fmaf(hB6,k6r, Zr)))));
            zi[u] = fmaf(hB1,k1i, fmaf(hB3,k3i, fmaf(hB4,k4i, fmaf(hB5,k5i, fmaf(hB6,k6i, Zi)))));
        }
    }

    // Output: stack([re, im]) -> first n reals, then n imags
    *(float2*)(out + i)     = make_float2(zr[0], zr[1]);
    *(float2*)(out + n + i) = make_float2(zi[0], zi[1]);
}

extern "C" void kernel_launch(void* const* d_in, const int* in_sizes, int n_in,
                              void* d_out, int out_size, void* d_ws, size_t ws_size,
                              hipStream_t stream) {
    const float* re_z = (const float*)d_in[0];
    const float* im_z = (const float*)d_in[1];
    const float* re_a = (const float*)d_in[2];
    const float* im_a = (const float*)d_in[3];
    const float* re_b = (const float*)d_in[4];
    const float* im_b = (const float*)d_in[5];
    // d_in[6] = stp (unused)
    const int*   unts = (const int*)d_in[7];
    float* out = (float*)d_out;

    const int n = in_sizes[0];                 // 2048*2048
    const int threads = (n + 1) / 2;           // 2 elements per thread
    const int block = 256;
    const int grid = (threads + block - 1) / block;

    hopf_dopri5_kernel<<<grid, block, 0, stream>>>(re_z, im_z, re_a, im_a,
                                                   re_b, im_b, unts, out, n);
}